// Round 9
// baseline (55.700 us; speedup 1.0000x reference)
//
#include <hip/hip_runtime.h>
#include <hip/hip_bf16.h>
#include <math.h>

#define BN 8
#define TT 128
#define DD 400
#define HH 300
#define LL 45
#define KH 200          // K half per in-block K-group (proj)
#define SS 129          // T+1 head candidates
#define ALG_STRIDE 132  // padded logit row
#define PADW 308        // LDS row pad (floats): 308%32=20 -> 8 consecutive rows
                        // start at disjoint 4-bank groups for b128 reads

// ---------------- Kernel A: projections ----------------
// grid = 129 blocks x 640 threads. blk<64: AP rows 16*blk.. ; blk<128: BPX rows;
// blk==128: root row for all b + zero accum. 16 rows/block halves weight
// re-read traffic vs 8 (61 MB total, L2-resident).
__global__ __launch_bounds__(640) void proj_kernel(
    const float* __restrict__ cont, const float* __restrict__ root,
    const float* __restrict__ W1a, const float* __restrict__ W1b,
    const float* __restrict__ b1,
    const int* __restrict__ slen,
    float* __restrict__ AP, float* __restrict__ BPX,
    float* __restrict__ accum)
{
    __shared__ float red[320][17];
    const int blk = blockIdx.x;
    const int tid = threadIdx.x;
    const int grp = tid / 320;                       // wave-aligned K-group
    const int h   = tid % 320;
    const int d0  = __builtin_amdgcn_readfirstlane(grp * KH);

    if (blk == 128) {
        if (tid == 0) accum[0] = 0.f;
        float acc = 0.f;
        if (h < HH) {
            const float* wp = W1b + (size_t)d0 * HH + h;
            for (int d = 0; d < KH; ++d)
                acc = fmaf(root[d0 + d], wp[(size_t)d * HH], acc);
        }
        if (grp == 1) red[h][0] = acc;
        __syncthreads();
        if (grp == 0 && h < HH) {
            const float v = acc + red[h][0];
            for (int bb = 0; bb < BN; ++bb)
                BPX[(size_t)bb * SS * HH + h] = v;   // root row per batch
        }
        return;
    }

    const bool isA = (blk < 64);
    const int rb   = isA ? blk : blk - 64;
    const int row0 = rb * 16;
    if (isA) {  // skip fully-masked AP row groups only (BPX rows all needed)
        const int lenb = slen[row0 >> 7];
        if ((row0 & 127) >= lenb) return;
    }

    const float* W    = isA ? W1a : W1b;
    const float* rows = cont + (size_t)row0 * DD + d0;

    float acc[16];
    #pragma unroll
    for (int r = 0; r < 16; ++r) acc[r] = 0.f;

    if (h < HH) {
        const float* wp = W + (size_t)d0 * HH + h;
        float w[8];
        #pragma unroll
        for (int k = 0; k < 8; ++k) w[k] = wp[(size_t)k * HH];
        for (int dc = 0; dc < KH; dc += 8) {
            float wn[8];
            if (dc + 8 < KH) {
                #pragma unroll
                for (int k = 0; k < 8; ++k) wn[k] = wp[(size_t)(dc + 8 + k) * HH];
            } else {
                #pragma unroll
                for (int k = 0; k < 8; ++k) wn[k] = 0.f;
            }
            #pragma unroll
            for (int r = 0; r < 16; ++r) {
                const float* rp = rows + r * DD + dc;   // block-uniform -> s_load
                #pragma unroll
                for (int k = 0; k < 8; ++k)
                    acc[r] = fmaf(rp[k], w[k], acc[r]);
            }
            #pragma unroll
            for (int k = 0; k < 8; ++k) w[k] = wn[k];
        }
    }

    if (grp == 1) {
        #pragma unroll
        for (int r = 0; r < 16; ++r) red[h][r] = acc[r];
    }
    __syncthreads();
    if (grp == 0 && h < HH) {
        if (isA) {
            const float bb = b1[h];
            float* dst = AP + (size_t)row0 * HH + h;
            #pragma unroll
            for (int r = 0; r < 16; ++r)
                dst[(size_t)r * HH] = acc[r] + red[h][r] + bb;
        } else {
            const int b = row0 >> 7, t = row0 & 127;
            float* dst = BPX + ((size_t)(b * SS + t + 1)) * HH + h;
            #pragma unroll
            for (int r = 0; r < 16; ++r)
                dst[(size_t)r * HH] = acc[r] + red[h][r];
        }
    }
}

// ---------------- Kernel B1: arc logits, lane-owns-(t,s) ----------------
// grid = 512: blk = b*64 + tt*4 + sc  (tt: 16 t-tiles of 8, sc: 4 s-chunks of 32)
// block = 256 (4 waves). Lane = 8*sl + tl. Wave w owns s_local = w*8+sl.
// All operands staged in LDS; inner loop = 3 ds_read_b128 + 12 VALU per 4h.
// No cross-lane reduction: each lane accumulates its full (t,s) dot product.
__global__ __launch_bounds__(256) void arc_kernel(
    const float* __restrict__ AP, const float* __restrict__ BPX,
    const float* __restrict__ Wa, const int* __restrict__ slen,
    float* __restrict__ ALG)
{
    __shared__ float ap_s[8][PADW];
    __shared__ float bp_s[33][PADW];
    __shared__ float wa_s[PADW];

    const int blk = blockIdx.x;
    const int b  = blk >> 6;
    const int tt = (blk >> 2) & 15;
    const int sc = blk & 3;
    const int t0 = tt * 8;
    if (t0 >= slen[b]) return;   // masked t-tile: its ALG rows are never read

    const int tid  = threadIdx.x;
    const int lane = tid & 63;
    const int wave = tid >> 6;
    const int tl   = lane & 7;
    const int sl   = lane >> 3;
    const int s0   = sc * 32;

    // Stage AP 8x300, BP 33x300 (rows s0..s0+32 all exist: s0+32 <= 128), Wa 300
    {
        const float* apg = AP + (size_t)(b * TT + t0) * HH;
        for (int i = tid; i < 8 * HH; i += 256)
            ap_s[i / HH][i % HH] = apg[(i / HH) * HH + i % HH];
        const float* bpg = BPX + (size_t)(b * SS + s0) * HH;
        for (int i = tid; i < 33 * HH; i += 256)
            bp_s[i / HH][i % HH] = bpg[(i / HH) * HH + i % HH];
        for (int i = tid; i < HH; i += 256)
            wa_s[i] = Wa[i];
    }
    __syncthreads();

    const int s_local = wave * 8 + sl;           // 0..31
    const float* aprow = ap_s[tl];
    const float* bprow = bp_s[s_local];

    float acc = 0.f;
    #pragma unroll 5
    for (int hh = 0; hh < HH; hh += 4) {
        const float4 a4 = *(const float4*)&aprow[hh];
        const float4 p4 = *(const float4*)&bprow[hh];
        const float4 w4 = *(const float4*)&wa_s[hh];
        acc = fmaf(fmaxf(a4.x + p4.x, 0.f), w4.x, acc);
        acc = fmaf(fmaxf(a4.y + p4.y, 0.f), w4.y, acc);
        acc = fmaf(fmaxf(a4.z + p4.z, 0.f), w4.z, acc);
        acc = fmaf(fmaxf(a4.w + p4.w, 0.f), w4.w, acc);
    }
    ALG[(size_t)(b * TT + t0 + tl) * ALG_STRIDE + s0 + s_local] = acc;

    // s = 128 (the 33rd staged row), only for the last chunk: 8 lanes of wave 0
    if (sc == 3 && wave == 0 && sl == 0) {
        const float* bpr = bp_s[32];
        float a2 = 0.f;
        #pragma unroll 5
        for (int hh = 0; hh < HH; hh += 4) {
            const float4 a4 = *(const float4*)&aprow[hh];
            const float4 p4 = *(const float4*)&bpr[hh];
            const float4 w4 = *(const float4*)&wa_s[hh];
            a2 = fmaf(fmaxf(a4.x + p4.x, 0.f), w4.x, a2);
            a2 = fmaf(fmaxf(a4.y + p4.y, 0.f), w4.y, a2);
            a2 = fmaf(fmaxf(a4.z + p4.z, 0.f), w4.z, a2);
            a2 = fmaf(fmaxf(a4.w + p4.w, 0.f), w4.w, a2);
        }
        ALG[(size_t)(b * TT + t0 + tl) * ALG_STRIDE + 128] = a2;
    }
}

// ---------------- Kernel B2: softmax + CE + label ----------------
// grid = 1024 = B*T, block = 256 (4 waves). Label GEMV h-split across waves.
__global__ __launch_bounds__(256) void smx_kernel(
    const float* __restrict__ AP, const float* __restrict__ BPX,
    const float* __restrict__ Wl, const float* __restrict__ bl,
    const float* __restrict__ ALG,
    const int* __restrict__ slen, const int* __restrict__ des_arcs,
    const int* __restrict__ des_labels, const int* __restrict__ use_des,
    float* __restrict__ accum)
{
    const int blk = blockIdx.x;
    const int b = blk >> 7, t = blk & 127;
    if (t >= slen[b]) return;
    const int tid  = threadIdx.x;
    const int lane = tid & 63;
    const int wave = tid >> 6;

    __shared__ float selh[HH];
    __shared__ float partial[4][64];
    __shared__ float arc_ce_s;
    __shared__ int   sel_s;

    // Phase 1 (wave 0): 129-way log-softmax + argmax + arc CE
    if (wave == 0) {
        const float* lg = ALG + (size_t)blk * ALG_STRIDE;
        const float v0 = lg[lane];
        const float v1 = lg[64 + lane];
        const float v2 = (lane == 0) ? lg[128] : -INFINITY;

        float m = fmaxf(fmaxf(v0, v1), v2);
        #pragma unroll
        for (int off = 32; off; off >>= 1) m = fmaxf(m, __shfl_xor(m, off, 64));
        float e = __expf(v0 - m) + __expf(v1 - m) + ((lane == 0) ? __expf(v2 - m) : 0.f);
        #pragma unroll
        for (int off = 32; off; off >>= 1) e += __shfl_xor(e, off, 64);
        const float arc_lse = m + __logf(e);

        float bv = v0; int bi = lane;
        if (v1 > bv) { bv = v1; bi = 64 + lane; }
        if (lane == 0 && v2 > bv) { bv = v2; bi = 128; }
        #pragma unroll
        for (int off = 32; off; off >>= 1) {
            const float ov = __shfl_xor(bv, off, 64);
            const int   oi = __shfl_xor(bi, off, 64);
            if (ov > bv || (ov == bv && oi < bi)) { bv = ov; bi = oi; }
        }
        if (lane == 0) {
            const int da = des_arcs[b * TT + t];
            arc_ce_s = arc_lse - lg[da];
            sel_s = use_des[0] ? da : bi;
        }
    }
    __syncthreads();

    // Phase 2: selected pair representation -> LDS (256 threads)
    {
        const int sel = sel_s;
        const float* ap = AP + (size_t)blk * HH;
        const float* bp = BPX + (size_t)(b * SS + sel) * HH;
        for (int hh = tid; hh < HH; hh += 256)
            selh[hh] = fmaxf(ap[hh] + bp[hh], 0.f);
    }
    __syncthreads();

    // Phase 3: label GEMV, wave w covers h in [w*75, w*75+75)
    {
        float p = 0.f;
        if (lane < LL) {
            const int h0 = wave * 75;
            #pragma unroll 5
            for (int j = 0; j < 75; ++j)
                p = fmaf(selh[h0 + j], Wl[(h0 + j) * LL + lane], p);
        }
        partial[wave][lane] = p;
    }
    __syncthreads();

    // Phase 4 (wave 0): combine partials, 45-way log-softmax, CE, accumulate
    if (wave == 0) {
        float a = -INFINITY;
        if (lane < LL)
            a = bl[lane] + partial[0][lane] + partial[1][lane]
                         + partial[2][lane] + partial[3][lane];
        float lm = a;
        #pragma unroll
        for (int off = 32; off; off >>= 1) lm = fmaxf(lm, __shfl_xor(lm, off, 64));
        float le = (lane < LL) ? __expf(a - lm) : 0.f;
        #pragma unroll
        for (int off = 32; off; off >>= 1) le += __shfl_xor(le, off, 64);
        const float lab_lse = lm + __logf(le);

        const int dl = des_labels[b * TT + t];
        const float ldl = __shfl(a, dl, 64);
        if (lane == 0)
            atomicAdd(accum, arc_ce_s + (lab_lse - ldl));
    }
}

// ---------------- Kernel C: finalize ----------------
__global__ void finalize_kernel(const float* __restrict__ accum,
                                const int* __restrict__ slen,
                                float* __restrict__ out)
{
    if (threadIdx.x == 0) {
        int n = 0;
        for (int b = 0; b < BN; ++b) {
            int l = slen[b];
            if (l < 0) l = 0;
            if (l > TT) l = TT;
            n += l;
        }
        float nv = (float)n;
        if (nv < 1.f) nv = 1.f;
        out[0] = accum[0] / (2.f * nv);
    }
}

extern "C" void kernel_launch(void* const* d_in, const int* in_sizes, int n_in,
                              void* d_out, int out_size, void* d_ws, size_t ws_size,
                              hipStream_t stream) {
    const float* cont = (const float*)d_in[0];
    const float* root = (const float*)d_in[1];
    const float* W1a  = (const float*)d_in[2];
    const float* W1b  = (const float*)d_in[3];
    const float* b1   = (const float*)d_in[4];
    const float* Wa   = (const float*)d_in[5];
    // d_in[6] = ba: cancels in CE and argmax -> unused
    const float* Wl   = (const float*)d_in[7];
    const float* bl   = (const float*)d_in[8];
    const int* slen   = (const int*)d_in[9];
    const int* darc   = (const int*)d_in[10];
    const int* dlab   = (const int*)d_in[11];
    const int* used   = (const int*)d_in[12];
    float* out = (float*)d_out;

    float* AP    = (float*)d_ws;              // 1024*300
    float* BPX   = AP  + 1024 * HH;           // 8*129*300
    float* ALG   = BPX + BN * SS * HH;        // 1024*132
    float* accum = ALG + 1024 * ALG_STRIDE;   // 1

    proj_kernel<<<129, 640, 0, stream>>>(cont, root, W1a, W1b, b1, slen, AP, BPX, accum);
    arc_kernel<<<512, 256, 0, stream>>>(AP, BPX, Wa, slen, ALG);
    smx_kernel<<<1024, 256, 0, stream>>>(AP, BPX, Wl, bl, ALG, slen, darc, dlab, used, accum);
    finalize_kernel<<<1, 64, 0, stream>>>(accum, slen, out);
}

// Round 10
// 47.108 us; speedup vs baseline: 1.1824x; 1.1824x over previous
//
#include <hip/hip_runtime.h>
#include <hip/hip_bf16.h>
#include <math.h>

#define BN 8
#define TT 128
#define DD 400
#define HH 300
#define LL 45
#define KH 200          // K half per in-block K-group (proj)
#define SS 129          // T+1 head candidates
#define ALG_STRIDE 132  // padded logit row
#define PADW 308        // LDS row pad (floats): 308%32=20 -> 8 consecutive rows
                        // start at disjoint 4-bank groups for b128 reads

// ---------------- Kernel A: projections ----------------
// grid = 257 blocks x 640 threads (10 waves).  [R8 config: 8 rows/block —
// 16 rows/block at grid 129 spilled acc[16] to scratch (VGPR=24) and idled
// half the CUs -> 50.7us. This config measured ~10us.]
//   blk <  128 : AP rows 8*blk..8*blk+7            (cont @ W1a + b1)
//   blk <  256 : BPX[b][t+1] rows for 8 t          (cont @ W1b)
//   blk == 256 : BPX[b][0] = root @ W1b for all b; zero accum
__global__ __launch_bounds__(640) void proj_kernel(
    const float* __restrict__ cont, const float* __restrict__ root,
    const float* __restrict__ W1a, const float* __restrict__ W1b,
    const float* __restrict__ b1,
    const int* __restrict__ slen,
    float* __restrict__ AP, float* __restrict__ BPX,
    float* __restrict__ accum)
{
    __shared__ float red[320][9];   // padded: conflict-free column access
    const int blk = blockIdx.x;
    const int tid = threadIdx.x;
    const int grp = tid / 320;                       // wave-aligned K-group
    const int h   = tid % 320;
    const int d0  = __builtin_amdgcn_readfirstlane(grp * KH);

    if (blk == 256) {
        if (tid == 0) accum[0] = 0.f;
        float acc = 0.f;
        if (h < HH) {
            const float* wp = W1b + (size_t)d0 * HH + h;
            for (int d = 0; d < KH; ++d)
                acc = fmaf(root[d0 + d], wp[(size_t)d * HH], acc);
        }
        if (grp == 1) red[h][0] = acc;
        __syncthreads();
        if (grp == 0 && h < HH) {
            const float v = acc + red[h][0];
            for (int bb = 0; bb < BN; ++bb)
                BPX[(size_t)bb * SS * HH + h] = v;   // root row per batch
        }
        return;
    }

    const bool isA = (blk < 128);
    const int rb   = isA ? blk : blk - 128;
    const int row0 = rb * 8;
    if (isA) {  // skip fully-masked AP row groups only (BPX rows all needed)
        const int lenb = slen[row0 >> 7];
        if ((row0 & 127) >= lenb) return;
    }

    const float* W    = isA ? W1a : W1b;
    const float* rows = cont + (size_t)row0 * DD + d0;

    float acc[8];
    #pragma unroll
    for (int r = 0; r < 8; ++r) acc[r] = 0.f;

    if (h < HH) {
        const float* wp = W + (size_t)d0 * HH + h;
        float w[8];
        #pragma unroll
        for (int k = 0; k < 8; ++k) w[k] = wp[(size_t)k * HH];
        for (int dc = 0; dc < KH; dc += 8) {
            float wn[8];
            if (dc + 8 < KH) {
                #pragma unroll
                for (int k = 0; k < 8; ++k) wn[k] = wp[(size_t)(dc + 8 + k) * HH];
            } else {
                #pragma unroll
                for (int k = 0; k < 8; ++k) wn[k] = 0.f;
            }
            #pragma unroll
            for (int r = 0; r < 8; ++r) {
                const float* rp = rows + r * DD + dc;   // block-uniform -> s_load
                #pragma unroll
                for (int k = 0; k < 8; ++k)
                    acc[r] = fmaf(rp[k], w[k], acc[r]);
            }
            #pragma unroll
            for (int k = 0; k < 8; ++k) w[k] = wn[k];
        }
    }

    if (grp == 1) {
        #pragma unroll
        for (int r = 0; r < 8; ++r) red[h][r] = acc[r];
    }
    __syncthreads();
    if (grp == 0 && h < HH) {
        if (isA) {
            const float bb = b1[h];
            float* dst = AP + (size_t)row0 * HH + h;
            #pragma unroll
            for (int r = 0; r < 8; ++r)
                dst[(size_t)r * HH] = acc[r] + red[h][r] + bb;
        } else {
            const int b = row0 >> 7, t = row0 & 127;
            float* dst = BPX + ((size_t)(b * SS + t + 1)) * HH + h;
            #pragma unroll
            for (int r = 0; r < 8; ++r)
                dst[(size_t)r * HH] = acc[r] + red[h][r];
        }
    }
}

// ---------------- Kernel B1: arc logits, lane-owns-(t,s) ----------------
// grid = 512: blk = b*64 + tt*4 + sc  (tt: 16 t-tiles of 8, sc: 4 s-chunks of 32)
// block = 256 (4 waves). Lane = 8*sl + tl. Wave w owns s_local = w*8+sl.
// All operands staged in LDS; no cross-lane ops in the inner loop.
__global__ __launch_bounds__(256) void arc_kernel(
    const float* __restrict__ AP, const float* __restrict__ BPX,
    const float* __restrict__ Wa, const int* __restrict__ slen,
    float* __restrict__ ALG)
{
    __shared__ float ap_s[8][PADW];
    __shared__ float bp_s[33][PADW];
    __shared__ float wa_s[PADW];

    const int blk = blockIdx.x;
    const int b  = blk >> 6;
    const int tt = (blk >> 2) & 15;
    const int sc = blk & 3;
    const int t0 = tt * 8;
    if (t0 >= slen[b]) return;   // masked t-tile: its ALG rows are never read

    const int tid  = threadIdx.x;
    const int lane = tid & 63;
    const int wave = tid >> 6;
    const int tl   = lane & 7;
    const int sl   = lane >> 3;
    const int s0   = sc * 32;

    // Stage AP 8x300, BP 33x300 (rows s0..s0+32 all exist: s0+32 <= 128), Wa 300
    {
        const float* apg = AP + (size_t)(b * TT + t0) * HH;
        for (int i = tid; i < 8 * HH; i += 256)
            ap_s[i / HH][i % HH] = apg[(i / HH) * HH + i % HH];
        const float* bpg = BPX + (size_t)(b * SS + s0) * HH;
        for (int i = tid; i < 33 * HH; i += 256)
            bp_s[i / HH][i % HH] = bpg[(i / HH) * HH + i % HH];
        for (int i = tid; i < HH; i += 256)
            wa_s[i] = Wa[i];
    }
    __syncthreads();

    const int s_local = wave * 8 + sl;           // 0..31
    const float* aprow = ap_s[tl];
    const float* bprow = bp_s[s_local];

    float acc = 0.f;
    #pragma unroll 5
    for (int hh = 0; hh < HH; hh += 4) {
        const float4 a4 = *(const float4*)&aprow[hh];
        const float4 p4 = *(const float4*)&bprow[hh];
        const float4 w4 = *(const float4*)&wa_s[hh];
        acc = fmaf(fmaxf(a4.x + p4.x, 0.f), w4.x, acc);
        acc = fmaf(fmaxf(a4.y + p4.y, 0.f), w4.y, acc);
        acc = fmaf(fmaxf(a4.z + p4.z, 0.f), w4.z, acc);
        acc = fmaf(fmaxf(a4.w + p4.w, 0.f), w4.w, acc);
    }
    ALG[(size_t)(b * TT + t0 + tl) * ALG_STRIDE + s0 + s_local] = acc;

    // s = 128 (the 33rd staged row), only for the last chunk: 8 lanes of wave 0
    if (sc == 3 && wave == 0 && sl == 0) {
        const float* bpr = bp_s[32];
        float a2 = 0.f;
        #pragma unroll 5
        for (int hh = 0; hh < HH; hh += 4) {
            const float4 a4 = *(const float4*)&aprow[hh];
            const float4 p4 = *(const float4*)&bpr[hh];
            const float4 w4 = *(const float4*)&wa_s[hh];
            a2 = fmaf(fmaxf(a4.x + p4.x, 0.f), w4.x, a2);
            a2 = fmaf(fmaxf(a4.y + p4.y, 0.f), w4.y, a2);
            a2 = fmaf(fmaxf(a4.z + p4.z, 0.f), w4.z, a2);
            a2 = fmaf(fmaxf(a4.w + p4.w, 0.f), w4.w, a2);
        }
        ALG[(size_t)(b * TT + t0 + tl) * ALG_STRIDE + 128] = a2;
    }
}

// ---------------- Kernel B2: softmax + CE + label ----------------
// grid = 1024 = B*T, block = 256 (4 waves). Label GEMV h-split across waves.
__global__ __launch_bounds__(256) void smx_kernel(
    const float* __restrict__ AP, const float* __restrict__ BPX,
    const float* __restrict__ Wl, const float* __restrict__ bl,
    const float* __restrict__ ALG,
    const int* __restrict__ slen, const int* __restrict__ des_arcs,
    const int* __restrict__ des_labels, const int* __restrict__ use_des,
    float* __restrict__ accum)
{
    const int blk = blockIdx.x;
    const int b = blk >> 7, t = blk & 127;
    if (t >= slen[b]) return;
    const int tid  = threadIdx.x;
    const int lane = tid & 63;
    const int wave = tid >> 6;

    __shared__ float selh[HH];
    __shared__ float partial[4][64];
    __shared__ float arc_ce_s;
    __shared__ int   sel_s;

    // Phase 1 (wave 0): 129-way log-softmax + argmax + arc CE
    if (wave == 0) {
        const float* lg = ALG + (size_t)blk * ALG_STRIDE;
        const float v0 = lg[lane];
        const float v1 = lg[64 + lane];
        const float v2 = (lane == 0) ? lg[128] : -INFINITY;

        float m = fmaxf(fmaxf(v0, v1), v2);
        #pragma unroll
        for (int off = 32; off; off >>= 1) m = fmaxf(m, __shfl_xor(m, off, 64));
        float e = __expf(v0 - m) + __expf(v1 - m) + ((lane == 0) ? __expf(v2 - m) : 0.f);
        #pragma unroll
        for (int off = 32; off; off >>= 1) e += __shfl_xor(e, off, 64);
        const float arc_lse = m + __logf(e);

        float bv = v0; int bi = lane;
        if (v1 > bv) { bv = v1; bi = 64 + lane; }
        if (lane == 0 && v2 > bv) { bv = v2; bi = 128; }
        #pragma unroll
        for (int off = 32; off; off >>= 1) {
            const float ov = __shfl_xor(bv, off, 64);
            const int   oi = __shfl_xor(bi, off, 64);
            if (ov > bv || (ov == bv && oi < bi)) { bv = ov; bi = oi; }
        }
        if (lane == 0) {
            const int da = des_arcs[b * TT + t];
            arc_ce_s = arc_lse - lg[da];
            sel_s = use_des[0] ? da : bi;
        }
    }
    __syncthreads();

    // Phase 2: selected pair representation -> LDS (256 threads)
    {
        const int sel = sel_s;
        const float* ap = AP + (size_t)blk * HH;
        const float* bp = BPX + (size_t)(b * SS + sel) * HH;
        for (int hh = tid; hh < HH; hh += 256)
            selh[hh] = fmaxf(ap[hh] + bp[hh], 0.f);
    }
    __syncthreads();

    // Phase 3: label GEMV, wave w covers h in [w*75, w*75+75)
    {
        float p = 0.f;
        if (lane < LL) {
            const int h0 = wave * 75;
            #pragma unroll 5
            for (int j = 0; j < 75; ++j)
                p = fmaf(selh[h0 + j], Wl[(h0 + j) * LL + lane], p);
        }
        partial[wave][lane] = p;
    }
    __syncthreads();

    // Phase 4 (wave 0): combine partials, 45-way log-softmax, CE, accumulate
    if (wave == 0) {
        float a = -INFINITY;
        if (lane < LL)
            a = bl[lane] + partial[0][lane] + partial[1][lane]
                         + partial[2][lane] + partial[3][lane];
        float lm = a;
        #pragma unroll
        for (int off = 32; off; off >>= 1) lm = fmaxf(lm, __shfl_xor(lm, off, 64));
        float le = (lane < LL) ? __expf(a - lm) : 0.f;
        #pragma unroll
        for (int off = 32; off; off >>= 1) le += __shfl_xor(le, off, 64);
        const float lab_lse = lm + __logf(le);

        const int dl = des_labels[b * TT + t];
        const float ldl = __shfl(a, dl, 64);
        if (lane == 0)
            atomicAdd(accum, arc_ce_s + (lab_lse - ldl));
    }
}

// ---------------- Kernel C: finalize ----------------
__global__ void finalize_kernel(const float* __restrict__ accum,
                                const int* __restrict__ slen,
                                float* __restrict__ out)
{
    if (threadIdx.x == 0) {
        int n = 0;
        for (int b = 0; b < BN; ++b) {
            int l = slen[b];
            if (l < 0) l = 0;
            if (l > TT) l = TT;
            n += l;
        }
        float nv = (float)n;
        if (nv < 1.f) nv = 1.f;
        out[0] = accum[0] / (2.f * nv);
    }
}

extern "C" void kernel_launch(void* const* d_in, const int* in_sizes, int n_in,
                              void* d_out, int out_size, void* d_ws, size_t ws_size,
                              hipStream_t stream) {
    const float* cont = (const float*)d_in[0];
    const float* root = (const float*)d_in[1];
    const float* W1a  = (const float*)d_in[2];
    const float* W1b  = (const float*)d_in[3];
    const float* b1   = (const float*)d_in[4];
    const float* Wa   = (const float*)d_in[5];
    // d_in[6] = ba: cancels in CE and argmax -> unused
    const float* Wl   = (const float*)d_in[7];
    const float* bl   = (const float*)d_in[8];
    const int* slen   = (const int*)d_in[9];
    const int* darc   = (const int*)d_in[10];
    const int* dlab   = (const int*)d_in[11];
    const int* used   = (const int*)d_in[12];
    float* out = (float*)d_out;

    float* AP    = (float*)d_ws;              // 1024*300
    float* BPX   = AP  + 1024 * HH;           // 8*129*300
    float* ALG   = BPX + BN * SS * HH;        // 1024*132
    float* accum = ALG + 1024 * ALG_STRIDE;   // 1

    proj_kernel<<<257, 640, 0, stream>>>(cont, root, W1a, W1b, b1, slen, AP, BPX, accum);
    arc_kernel<<<512, 256, 0, stream>>>(AP, BPX, Wa, slen, ALG);
    smx_kernel<<<1024, 256, 0, stream>>>(AP, BPX, Wl, bl, ALG, slen, darc, dlab, used, accum);
    finalize_kernel<<<1, 64, 0, stream>>>(accum, slen, out);
}